// Round 4
// baseline (507.536 us; speedup 1.0000x reference)
//
#include <hip/hip_runtime.h>
#include <stdint.h>

#define C_IN 128
#define NUMD 524288
#define LNUMD 32768
#define NNUM_DM1 (LNUMD + NUMD/8)
#define PREFIX 16384
#define N_CONV (PREFIX + NNUM_DM1)   // 114688
#define N_EDGES (N_CONV * 7)         // 802816
#define ND8 (NUMD/8)                 // 65536
#define KCP 960                      // 7 blocks of 136 (128 ch + 7 onehot + 1 pad) + 8 pad
#define AGG_STRIDE 968

#define HIST_BLK (N_EDGES/256)               // 3136
#define COPY_BLK ((PREFIX+LNUMD)*32/256)     // 6144
#define PREPW_BLK ((128*KCP + 128*1024)/256) // 992
#define SCAT_BLK (N_EDGES/256)               // 3136
#define DOWN_BLK (ND8/64)                    // 1024

#define CONV_BLK 512
#define CONV_ITER (N_CONV/16/CONV_BLK)       // 14
#define EBATCH 12

typedef __attribute__((ext_vector_type(8))) short short8;
typedef __attribute__((ext_vector_type(4))) float f32x4;

__device__ inline ushort f2b(float f){
  union { float f; uint32_t u; } v; v.f = f;
  uint32_t r = v.u + 0x7fffu + ((v.u >> 16) & 1u);
  return (ushort)(r >> 16);
}
__device__ inline float b2f_lo(uint32_t u){ union { uint32_t u; float f; } v; v.u = u << 16; return v.f; }
__device__ inline float b2f_hi(uint32_t u){ union { uint32_t u; float f; } v; v.u = u & 0xffff0000u; return v.f; }

// ---- fused: hist | copy prefix+leaf rows | weight conversion ----
__global__ void k_prep(const float* __restrict__ x, const float* __restrict__ wconv,
                       const float* __restrict__ wdown, const int* __restrict__ ei,
                       ushort* __restrict__ xconv, ushort* __restrict__ w16t,
                       ushort* __restrict__ wd16, int* __restrict__ cnt){
  const int bid = blockIdx.x;
  if (bid < HIST_BLK){
    int e = bid*256 + threadIdx.x;
    atomicAdd(&cnt[ei[e]], 1);
  } else if (bid < HIST_BLK + COPY_BLK){
    int gid = (bid - HIST_BLK)*256 + threadIdx.x;
    int row = gid >> 5, seg = (gid & 31) * 4;
    int srow, drow;
    if (row < PREFIX){ srow = row; drow = row; }
    else { int k = row - PREFIX; srow = PREFIX + k; drow = PREFIX + 3*k; }
    const float4 f = *(const float4*)(x + (size_t)srow*C_IN + seg);
    ushort4 o; o.x=f2b(f.x); o.y=f2b(f.y); o.z=f2b(f.z); o.w=f2b(f.w);
    *(ushort4*)(xconv + (size_t)drow*C_IN + seg) = o;
  } else {
    int gid = (bid - HIST_BLK - COPY_BLK)*256 + threadIdx.x;
    if (gid < 128*KCP){
      // padded layout: k = t*136 + c, c<135 -> wconv[t*135+c][o], else 0
      int o = gid / KCP, k = gid - o*KCP;
      float v = 0.f;
      if (k < 952){
        int t = k / 136, c = k - t*136;
        if (c < 135) v = wconv[(size_t)(t*135 + c)*128 + o];
      }
      w16t[gid] = f2b(v);
    } else {
      int i = gid - 128*KCP;
      wd16[i] = f2b(wdown[i]);
    }
  }
}

// ---- 3-stage coalesced scan of cnt[N_CONV] -> row_ptr + cursor ----
__global__ void k_scanA(const int* __restrict__ cnt, int* __restrict__ bsum){
  __shared__ int r[256];
  const int t = threadIdx.x, base = blockIdx.x*1024;
  int s = cnt[base+t] + cnt[base+t+256] + cnt[base+t+512] + cnt[base+t+768];
  r[t] = s; __syncthreads();
  for (int off=128; off>0; off>>=1){ if (t<off) r[t]+=r[t+off]; __syncthreads(); }
  if (t==0) bsum[blockIdx.x] = r[0];
}

__global__ void k_scanB(int* __restrict__ bsum){
  __shared__ int ps[128];
  const int t = threadIdx.x;
  int v = (t < 112) ? bsum[t] : 0;
  ps[t] = v; __syncthreads();
  for (int off=1; off<128; off<<=1){
    int val = ps[t];
    int add = (t>=off) ? ps[t-off] : 0;
    __syncthreads();
    ps[t] = val + add;
    __syncthreads();
  }
  int excl = (t==0) ? 0 : ps[t-1];
  if (t < 112) bsum[t] = excl;
}

__global__ void k_scanC(int* __restrict__ cnt, const int* __restrict__ bsum,
                        int* __restrict__ row_ptr){
  __shared__ int ps[256];
  const int b = blockIdx.x, t = threadIdx.x;
  int4 v = *(const int4*)(cnt + b*1024 + t*4);
  int s0 = v.x, s1 = s0+v.y, s2 = s1+v.z, s3 = s2+v.w;
  ps[t] = s3; __syncthreads();
  for (int off=1; off<256; off<<=1){
    int val = ps[t];
    int add = (t>=off) ? ps[t-off] : 0;
    __syncthreads();
    ps[t] = val + add;
    __syncthreads();
  }
  int excl = ((t==0) ? 0 : ps[t-1]) + bsum[b];
  int4 rp; rp.x = excl; rp.y = excl+s0; rp.z = excl+s1; rp.w = excl+s2;
  *(int4*)(row_ptr + b*1024 + t*4) = rp;
  *(int4*)(cnt + b*1024 + t*4) = rp;            // becomes cursor
  if (b == 111 && t == 255) row_ptr[N_CONV] = excl + s3;
}

// ---- fused: edge scatter (packed col|type|ntype) | down-projection GEMM ----
__global__ __launch_bounds__(256) void k_sd(const int* __restrict__ ei, const int* __restrict__ et,
    const int* __restrict__ ntype, int* __restrict__ cur, int* __restrict__ csp,
    const float* __restrict__ x, const ushort* __restrict__ wd16, ushort* __restrict__ xconv){
  const int bid = blockIdx.x;
  if (bid < SCAT_BLK){
    int e = bid*256 + threadIdx.x;
    int r = ei[e], c = ei[N_EDGES + e], t = et[e];
    int nt_ = ntype[c];
    int pos = atomicAdd(&cur[r], 1);
    csp[pos] = c | (t << 17) | (nt_ << 20);
    return;
  }
  __shared__ ushort at[64][56];
  const int tid = threadIdx.x;
  const int n0 = (bid - SCAT_BLK) * 64;
  const float* xd = x + (size_t)(PREFIX+LNUMD)*C_IN;
  const int wid = tid >> 6, l = tid & 63;
  const int arow = l & 15, kgrp = l >> 4;
  f32x4 acc[8];
  #pragma unroll
  for (int s=0;s<8;s++) acc[s] = (f32x4){0.f,0.f,0.f,0.f};
  const int srow = tid >> 2, kseg = (tid & 3) * 8;
  for (int k0 = 0; k0 < 1024; k0 += 32){
    __syncthreads();
    const float* src = xd + (size_t)(n0+srow)*1024 + k0 + kseg;
    float4 f0 = *(const float4*)src;
    float4 f1 = *(const float4*)(src+4);
    uint4 pk;
    pk.x = (uint)f2b(f0.x) | ((uint)f2b(f0.y)<<16);
    pk.y = (uint)f2b(f0.z) | ((uint)f2b(f0.w)<<16);
    pk.z = (uint)f2b(f1.x) | ((uint)f2b(f1.y)<<16);
    pk.w = (uint)f2b(f1.z) | ((uint)f2b(f1.w)<<16);
    *(uint4*)&at[srow][kseg] = pk;
    __syncthreads();
    short8 a = *(const short8*)&at[16*wid + arow][kgrp*8];
    #pragma unroll
    for (int s=0;s<8;s++){
      short8 b = *(const short8*)(wd16 + (size_t)(s*16 + arow)*1024 + k0 + kgrp*8);
      acc[s] = __builtin_amdgcn_mfma_f32_16x16x32_bf16(a, b, acc[s], 0,0,0);
    }
  }
  #pragma unroll
  for (int s=0;s<8;s++){
    int col = s*16 + arow;
    #pragma unroll
    for (int r=0;r<4;r++){
      int n = n0 + 16*wid + kgrp*4 + r;
      int i = 3*(n>>1) + 1 + (n&1);
      xconv[(size_t)(PREFIX + i)*C_IN + col] = f2b(acc[s][r]);
    }
  }
}

// ---- persistent-block pipelined aggregation + GEMM ----
// 512 threads: 16 slots x 32 lanes; M=16 vertices per group, 14 groups per block.
__global__ __launch_bounds__(512, 4) void k_conv(const int* __restrict__ row_ptr,
    const int* __restrict__ csp, const ushort* __restrict__ xconv,
    const ushort* __restrict__ w16t, float* __restrict__ out){
  __shared__ ushort agg[16][AGG_STRIDE];
  const int tid = threadIdx.x;
  const int slot = tid >> 5, lane = tid & 31;

  // zero pad columns once (positions t*136+135 and 952..959; never written by dumps)
  if (tid < 256){
    int s = tid >> 4, q = tid & 15;
    agg[s][q < 7 ? q*136 + 135 : 945 + q] = 0;
  }

  int g = blockIdx.x;
  int v = g*16 + slot;
  int e0c = row_ptr[v], e1c = row_ptr[v+1];
  int meta[EBATCH];
  uint2 d[EBATCH];
  {
    int n = min(e1c - e0c, EBATCH);
    #pragma unroll
    for (int i=0;i<EBATCH;i++) if (i < n) meta[i] = csp[e0c + i];
    #pragma unroll
    for (int i=0;i<EBATCH;i++) if (i < n)
      d[i] = *(const uint2*)(xconv + (size_t)(meta[i] & 0x1FFFF)*C_IN + lane*4);
  }

  for (int iter = 0;; ){
    const int gn = g + CONV_BLK;
    const bool more = (iter + 1 < CONV_ITER);
    int e0n = 0, e1n = 0;
    if (more){                                  // issue rp(next) early
      int vn = gn*16 + slot;
      e0n = row_ptr[vn]; e1n = row_ptr[vn+1];
    }

    // accumulate current group's gathers
    float a0[4],a1[4],a2[4],a3[4],a4[4],a5[4],a6[4];
    #pragma unroll
    for (int j=0;j<4;j++){ a0[j]=0;a1[j]=0;a2[j]=0;a3[j]=0;a4[j]=0;a5[j]=0;a6[j]=0; }
    float c0 = 0.f, c1 = 0.f;
    const int nc = min(e1c - e0c, EBATCH);
    #pragma unroll
    for (int i=0;i<EBATCH;i++){
      if (i < nc){
        float f[4];
        f[0]=b2f_lo(d[i].x); f[1]=b2f_hi(d[i].x);
        f[2]=b2f_lo(d[i].y); f[3]=b2f_hi(d[i].y);
        int t = (meta[i] >> 17) & 7;
        #define ADDC(A) { _Pragma("unroll") for(int j=0;j<4;j++) A[j]+=f[j]; }
        switch(t){
          case 0: ADDC(a0); break; case 1: ADDC(a1); break;
          case 2: ADDC(a2); break; case 3: ADDC(a3); break;
          case 4: ADDC(a4); break; case 5: ADDC(a5); break;
          default: ADDC(a6); break;
        }
        int combo = t*7 + ((meta[i] >> 20) & 7);
        c0 += (combo == lane) ? 1.f : 0.f;
        c1 += (combo == lane + 32) ? 1.f : 0.f;
      }
    }
    // rare serial remainder (n > EBATCH)
    for (int e = e0c + EBATCH; e < e1c; ++e){
      int cp = csp[e];
      uint2 dd = *(const uint2*)(xconv + (size_t)(cp & 0x1FFFF)*C_IN + lane*4);
      float f[4];
      f[0]=b2f_lo(dd.x); f[1]=b2f_hi(dd.x);
      f[2]=b2f_lo(dd.y); f[3]=b2f_hi(dd.y);
      int t = (cp >> 17) & 7;
      switch(t){
        case 0: ADDC(a0); break; case 1: ADDC(a1); break;
        case 2: ADDC(a2); break; case 3: ADDC(a3); break;
        case 4: ADDC(a4); break; case 5: ADDC(a5); break;
        default: ADDC(a6); break;
      }
      #undef ADDC
      int combo = t*7 + ((cp >> 20) & 7);
      c0 += (combo == lane) ? 1.f : 0.f;
      c1 += (combo == lane + 32) ? 1.f : 0.f;
    }

    // issue next group's meta loads (overlap with dump VALU)
    int nn = 0;
    if (more){
      nn = min(e1n - e0n, EBATCH);
      #pragma unroll
      for (int i=0;i<EBATCH;i++) if (i < nn) meta[i] = csp[e0n + i];
    }

    // dump acc -> LDS (packed b64 writes)
    #define DUMP(A,T) { uint2 pk; \
      pk.x = (uint)f2b(A[0]) | ((uint)f2b(A[1])<<16); \
      pk.y = (uint)f2b(A[2]) | ((uint)f2b(A[3])<<16); \
      *(uint2*)&agg[slot][T*136 + lane*4] = pk; }
    DUMP(a0,0) DUMP(a1,1) DUMP(a2,2) DUMP(a3,3) DUMP(a4,4) DUMP(a5,5) DUMP(a6,6)
    #undef DUMP
    agg[slot][(lane/7)*136 + 128 + (lane%7)] = f2b(c0);
    if (lane < 17) agg[slot][((lane+32)/7)*136 + 128 + ((lane+32)%7)] = f2b(c1);

    // issue next group's gathers (in flight across the GEMM)
    if (more){
      #pragma unroll
      for (int i=0;i<EBATCH;i++) if (i < nn)
        d[i] = *(const uint2*)(xconv + (size_t)(meta[i] & 0x1FFFF)*C_IN + lane*4);
    }
    __syncthreads();

    // GEMM: (16 x 960) @ (960 x 128); 8 waves, 16 cols each
    {
      const int wid = tid >> 6, l = tid & 63;
      const int arow = l & 15, kgrp = l >> 4;
      const int cb = wid * 16;
      f32x4 acc = {0.f,0.f,0.f,0.f};
      const ushort* wrow = w16t + (size_t)(cb + arow)*KCP + kgrp*8;
      #pragma unroll 6
      for (int k0 = 0; k0 < KCP; k0 += 32){
        short8 a = *(const short8*)&agg[arow][k0 + kgrp*8];
        short8 b = *(const short8*)(wrow + k0);
        acc = __builtin_amdgcn_mfma_f32_16x16x32_bf16(a, b, acc, 0,0,0);
      }
      #pragma unroll
      for (int r = 0; r < 4; r++)
        out[(size_t)(g*16 + kgrp*4 + r)*C_IN + cb + arow] = acc[r];
    }

    if (++iter >= CONV_ITER) break;
    g = gn; e0c = e0n; e1c = e1n;
    __syncthreads();                            // protect agg before next dump
  }
}

extern "C" void kernel_launch(void* const* d_in, const int* in_sizes, int n_in,
                              void* d_out, int out_size, void* d_ws, size_t ws_size,
                              hipStream_t stream){
  const float* x     = (const float*)d_in[0];
  const int*   ei    = (const int*)d_in[2];
  const int*   et    = (const int*)d_in[3];
  const int*   nt    = (const int*)d_in[4];
  const float* wdown = (const float*)d_in[5];
  const float* wconv = (const float*)d_in[6];
  float* out = (float*)d_out;

  char* p = (char*)d_ws;
  ushort* xconv = (ushort*)p; p += (size_t)N_CONV*C_IN*2;
  ushort* w16t  = (ushort*)p; p += (size_t)128*KCP*2;
  ushort* wd16  = (ushort*)p; p += (size_t)128*1024*2;
  int* cnt      = (int*)p;    p += (size_t)N_CONV*4;
  int* row_ptr  = (int*)p;    p += (size_t)(N_CONV+64)*4;
  int* bsum     = (int*)p;    p += 512;
  int* csp      = (int*)p;    p += (size_t)N_EDGES*4;

  hipMemsetAsync(cnt, 0, (size_t)N_CONV*4, stream);
  k_prep<<<HIST_BLK + COPY_BLK + PREPW_BLK, 256, 0, stream>>>(x, wconv, wdown, ei, xconv, w16t, wd16, cnt);
  k_scanA<<<112, 256, 0, stream>>>(cnt, bsum);
  k_scanB<<<1, 128, 0, stream>>>(bsum);
  k_scanC<<<112, 256, 0, stream>>>(cnt, bsum, row_ptr);
  k_sd<<<SCAT_BLK + DOWN_BLK, 256, 0, stream>>>(ei, et, nt, cnt, csp, x, wd16, xconv);
  k_conv<<<CONV_BLK, 512, 0, stream>>>(row_ptr, csp, xconv, w16t, out);
}